// Round 1
// baseline (6195.660 us; speedup 1.0000x reference)
//
#include <hip/hip_runtime.h>

#define BB 16
#define SS 1024
#define NPAD 1024      // padded matrix dim: real 1023 + identity pad row/col
#define NBLK 128
#define NSTEP 8        // NPAD / NBLK

// ---------- helpers ----------
__device__ __forceinline__ unsigned int enc_f32(float f) {
  unsigned int u = __float_as_uint(f);
  return (u & 0x80000000u) ? ~u : (u | 0x80000000u);
}
__device__ __forceinline__ float dec_key(unsigned int k) {
  unsigned int u = (k & 0x80000000u) ? (k & 0x7fffffffu) : ~k;
  return __uint_as_float(u);
}

// ---------- K0: init max key ----------
__global__ void __launch_bounds__(64) kinit(unsigned long long* mk) { *mk = 0ull; }

// ---------- K1: global max + argmax of scores ----------
__global__ void __launch_bounds__(256) kmax(const float* __restrict__ sc,
                                            unsigned long long* __restrict__ mk) {
  __shared__ unsigned long long red[256];
  const long long n = (long long)BB * SS * SS;
  unsigned long long best = 0ull;
  for (long long i = (long long)blockIdx.x * 256 + threadIdx.x; i < n;
       i += (long long)gridDim.x * 256) {
    unsigned long long k = ((unsigned long long)enc_f32(sc[i]) << 32) | (unsigned int)i;
    if (k > best) best = k;
  }
  red[threadIdx.x] = best;
  __syncthreads();
  for (int s = 128; s > 0; s >>= 1) {
    if ((int)threadIdx.x < s) {
      unsigned long long o = red[threadIdx.x + s];
      if (o > red[threadIdx.x]) red[threadIdx.x] = o;
    }
    __syncthreads();
  }
  if (threadIdx.x == 0) atomicMax(mk, red[0]);
}

// ---------- K2: build padded Laplacian minor M (row-dd M-matrix) ----------
// M[b][r][c] (r,c in 0..1023): for r<1023: delta_rc*rs_{r+1} - A[r+1][c+1] (c<1023), col 1023 = 0
// row 1023 = e_1023 (identity pad)
__global__ void __launch_bounds__(256) kbuild(const float* __restrict__ sc,
                                              float* __restrict__ M,
                                              const unsigned long long* __restrict__ mk) {
  __shared__ float red[256];
  const int r = blockIdx.x;
  const int b = blockIdx.y;
  const int t = threadIdx.x;
  float* Mrow = M + ((size_t)b * NPAD + r) * NPAD;
  if (r == NPAD - 1) {
    for (int c = t; c < NPAD; c += 256) Mrow[c] = (c == NPAD - 1) ? 1.0f : 0.0f;
    return;
  }
  const float m = dec_key((unsigned int)(*mk >> 32));
  const int i = r + 1;
  const float* srow = sc + ((size_t)b * SS + i) * SS;
  float part = 0.f;
  for (int j = t; j < SS; j += 256) part += expf(srow[j] - m);
  red[t] = part;
  __syncthreads();
  for (int s = 128; s > 0; s >>= 1) {
    if (t < s) red[t] += red[t + s];
    __syncthreads();
  }
  const float rs = red[0];
  for (int c = t; c < NPAD; c += 256) {
    float v;
    if (c == NPAD - 1) v = 0.0f;
    else {
      v = -expf(srow[c + 1] - m);
      if (c == r) v += rs;
    }
    Mrow[c] = v;
  }
}

// ---------- K3a: copy block column kb of M into T ----------
__global__ void __launch_bounds__(256) kcopy(const float* __restrict__ M,
                                             float* __restrict__ T, int kb) {
  const int rt = blockIdx.x, b = blockIdx.y, t = threadIdx.x;
  const float* src = M + ((size_t)b * NPAD + rt * NBLK) * NPAD + kb * NBLK;
  float* dst = T + ((size_t)b * NPAD + rt * NBLK) * NBLK;
  const int c = (t & 31) * 4, r0 = t >> 5;
  for (int r = r0; r < NBLK; r += 8) {
    float4 v = *(const float4*)(src + (size_t)r * NPAD + c);
    *(float4*)(dst + r * NBLK + c) = v;
  }
}

// ---------- K3b: invert 128x128 diag block (register-resident Gauss-Jordan) ----------
__global__ void __launch_bounds__(256) kdiaginv(const float* __restrict__ T,
                                                float* __restrict__ D, int kb) {
  __shared__ float rowbuf[NBLK];
  __shared__ float colbuf[NBLK];
  __shared__ float ps_s;
  const int b = blockIdx.x;
  const int t = threadIdx.x, tx = t & 15, ty = t >> 4;
  const float* src = T + ((size_t)b * NPAD + kb * NBLK) * NBLK;
  float r[8][8];
#pragma unroll
  for (int ii = 0; ii < 8; ii++)
#pragma unroll
    for (int jj = 0; jj < 8; jj++)
      r[ii][jj] = src[(ty + 16 * ii) * NBLK + tx + 16 * jj];

  for (int kk = 0; kk < NBLK; ++kk) {
    const int km = kk & 15, kd = kk >> 4;
    if (ty == km && tx == km) ps_s = 1.0f / r[kd][kd];
    __syncthreads();
    const float p = ps_s;
    if (ty == km) {
#pragma unroll
      for (int jj = 0; jj < 8; jj++) {
        float v = (tx == km && jj == kd) ? p : r[kd][jj] * p;
        r[kd][jj] = v;
        rowbuf[tx + 16 * jj] = v;
      }
    }
    if (tx == km) {
#pragma unroll
      for (int ii = 0; ii < 8; ii++) colbuf[ty + 16 * ii] = r[ii][kd];
    }
    __syncthreads();
#pragma unroll
    for (int ii = 0; ii < 8; ii++) {
      const int i = ty + 16 * ii;
      if (i == kk) continue;
      const float c = colbuf[i];
#pragma unroll
      for (int jj = 0; jj < 8; jj++) {
        const int j = tx + 16 * jj;
        float old = (j == kk) ? 0.0f : r[ii][jj];
        r[ii][jj] = old - c * rowbuf[j];
      }
    }
    __syncthreads();
  }
  float* dst = D + (size_t)b * NBLK * NBLK;
#pragma unroll
  for (int ii = 0; ii < 8; ii++)
#pragma unroll
    for (int jj = 0; jj < 8; jj++)
      dst[(ty + 16 * ii) * NBLK + tx + 16 * jj] = r[ii][jj];
}

// ---------- shared 128x128x128 fp32 GEMM core: C = beta*C + alpha*A*B ----------
__device__ __forceinline__ void gemm128(const float* __restrict__ A, int lda,
                                        const float* __restrict__ B, int ldb,
                                        float* __restrict__ C, int ldc,
                                        float alpha, float beta) {
  __shared__ float As[16][132];  // As[k][i] = A[i][k0+k] (transposed; +4 pad -> 2-way max)
  __shared__ float Bs[16][128];  // Bs[k][j] = B[k0+k][j]
  const int t = threadIdx.x, tx = t & 15, ty = t >> 4;
  float acc[8][8];
#pragma unroll
  for (int ii = 0; ii < 8; ii++)
#pragma unroll
    for (int jj = 0; jj < 8; jj++) acc[ii][jj] = 0.f;

  for (int k0 = 0; k0 < NBLK; k0 += 16) {
    {
      const int k = t & 15, i0 = t >> 4;
#pragma unroll
      for (int rr = 0; rr < 8; ++rr) {
        const int i = i0 + 16 * rr;
        As[k][i] = A[(size_t)i * lda + k0 + k];
      }
      const int j = t & 127, kb0 = t >> 7;
#pragma unroll
      for (int rr = 0; rr < 8; ++rr) {
        const int k2 = kb0 + 2 * rr;
        Bs[k2][j] = B[(size_t)(k0 + k2) * ldb + j];
      }
    }
    __syncthreads();
#pragma unroll
    for (int k = 0; k < 16; ++k) {
      float a[8], bv[8];
#pragma unroll
      for (int ii = 0; ii < 8; ii++) a[ii] = As[k][ty + 16 * ii];
#pragma unroll
      for (int jj = 0; jj < 8; jj++) bv[jj] = Bs[k][tx + 16 * jj];
#pragma unroll
      for (int ii = 0; ii < 8; ii++)
#pragma unroll
        for (int jj = 0; jj < 8; jj++) acc[ii][jj] += a[ii] * bv[jj];
    }
    __syncthreads();
  }
#pragma unroll
  for (int ii = 0; ii < 8; ii++)
#pragma unroll
    for (int jj = 0; jj < 8; jj++) {
      const int i = ty + 16 * ii, j = tx + 16 * jj;
      float* cp = C + (size_t)i * ldc + j;
      *cp = beta * (*cp) + alpha * acc[ii][jj];
    }
}

// ---------- K3c: pivot block-row scale: M[kb][jt] = Dinv * M[kb][jt]; M[kb][kb] = Dinv ----------
__global__ void __launch_bounds__(256) kscale(float* __restrict__ M,
                                              const float* __restrict__ D, int kb) {
  const int jt = blockIdx.x, b = blockIdx.y;
  const float* Dinv = D + (size_t)b * NBLK * NBLK;
  float* Mb = M + (size_t)b * NPAD * NPAD;
  if (jt == kb) {
    const int t = threadIdx.x;
    const int c = (t & 31) * 4, r0 = t >> 5;
    float* dst = Mb + (size_t)(kb * NBLK) * NPAD + kb * NBLK;
    for (int r = r0; r < NBLK; r += 8)
      *(float4*)(dst + (size_t)r * NPAD + c) = *(const float4*)(Dinv + r * NBLK + c);
    return;
  }
  float* Btile = Mb + (size_t)(kb * NBLK) * NPAD + jt * NBLK;
  gemm128(Dinv, NBLK, Btile, NPAD, Btile, NPAD, 1.0f, 0.0f);
}

// ---------- K3d: trailing update (and pivot-column): rows it != kb ----------
__global__ void __launch_bounds__(256) kupdate(float* __restrict__ M,
                                               const float* __restrict__ T,
                                               const float* __restrict__ D, int kb) {
  const int jt = blockIdx.x;
  int it = blockIdx.y; it = (it >= kb) ? it + 1 : it;
  const int b = blockIdx.z;
  float* Mb = M + (size_t)b * NPAD * NPAD;
  const float* Atile = T + ((size_t)b * NPAD + it * NBLK) * NBLK;  // old col panel, ld NBLK
  float* Ctile = Mb + (size_t)(it * NBLK) * NPAD + jt * NBLK;
  if (jt == kb) {
    // M[it][kb] = -T[it] * Dinv
    gemm128(Atile, NBLK, D + (size_t)b * NBLK * NBLK, NBLK, Ctile, NPAD, -1.0f, 0.0f);
  } else {
    // M[it][jt] -= T[it] * M[kb][jt]   (M[kb][jt] already scaled by kscale)
    const float* Btile = Mb + (size_t)(kb * NBLK) * NPAD + jt * NBLK;
    gemm128(Atile, NBLK, Btile, NPAD, Ctile, NPAD, -1.0f, 1.0f);
  }
}

// ---------- K4: epilogue: probs = A .* (Binv[p,p] - Binv[q,p]) + spike ----------
__global__ void __launch_bounds__(256) kfinal(const float* __restrict__ sc,
                                              const float* __restrict__ Minv,
                                              float* __restrict__ out,
                                              const unsigned long long* __restrict__ mk) {
  __shared__ float Ls[64][65];
  __shared__ float Ds[64];
  const int qt = blockIdx.x, pt = blockIdx.y, b = blockIdx.z;
  const int t = threadIdx.x;
  const unsigned long long key = *mk;
  const float m = dec_key((unsigned int)(key >> 32));
  const unsigned int amax = (unsigned int)key;
  const float* Mb = Minv + (size_t)b * NPAD * NPAD;
  const int q0 = qt * 64, p0 = pt * 64;
  {
    const int pp = t & 63, qq0 = t >> 6;
#pragma unroll
    for (int rp = 0; rp < 16; ++rp) {
      const int qq = qq0 + 4 * rp;
      int rrow = q0 + qq - 1; if (rrow < 0) rrow = 0;
      int ccol = p0 + pp - 1; if (ccol < 0) ccol = 0;
      Ls[qq][pp] = Mb[(size_t)rrow * NPAD + ccol];
    }
    if (t < 64) {
      int cc = p0 + t - 1; if (cc < 0) cc = 0;
      Ds[t] = Mb[(size_t)cc * NPAD + cc];
    }
  }
  __syncthreads();
  const int qq = t & 63, pp0 = t >> 6;
#pragma unroll
  for (int rp = 0; rp < 16; ++rp) {
    const int pp = pp0 + 4 * rp;
    const int p = p0 + pp, q = q0 + qq;
    const size_t off = ((size_t)b * SS + p) * SS + q;
    float val = 0.f;
    if (p >= 1) {
      const float a = expf(sc[off] - m);
      const float g = Ds[pp] - ((q >= 1) ? Ls[qq][pp] : 0.f);
      val = a * g;
    }
    if ((unsigned int)off == amax) val += 16.0f;  // d logZ / d m = B*lens - B*(S-1) = 16
    out[off] = val;
  }
}

extern "C" void kernel_launch(void* const* d_in, const int* in_sizes, int n_in,
                              void* d_out, int out_size, void* d_ws, size_t ws_size,
                              hipStream_t stream) {
  const float* sc = (const float*)d_in[0];
  float* out = (float*)d_out;
  char* ws = (char*)d_ws;
  unsigned long long* mk = (unsigned long long*)ws;
  float* M = (float*)(ws + 256);
  float* T = M + (size_t)BB * NPAD * NPAD;
  float* D = T + (size_t)BB * NPAD * NBLK;

  hipLaunchKernelGGL(kinit, dim3(1), dim3(64), 0, stream, mk);
  hipLaunchKernelGGL(kmax, dim3(1024), dim3(256), 0, stream, sc, mk);
  hipLaunchKernelGGL(kbuild, dim3(NPAD, BB), dim3(256), 0, stream, sc, M, mk);
  for (int kb = 0; kb < NSTEP; ++kb) {
    hipLaunchKernelGGL(kcopy, dim3(NSTEP, BB), dim3(256), 0, stream, M, T, kb);
    hipLaunchKernelGGL(kdiaginv, dim3(BB), dim3(256), 0, stream, T, D, kb);
    hipLaunchKernelGGL(kscale, dim3(NSTEP, BB), dim3(256), 0, stream, M, D, kb);
    hipLaunchKernelGGL(kupdate, dim3(NSTEP, NSTEP - 1, BB), dim3(256), 0, stream, M, T, D, kb);
  }
  hipLaunchKernelGGL(kfinal, dim3(16, 16, BB), dim3(256), 0, stream, sc, M, out, mk);
}

// Round 2
// 1644.979 us; speedup vs baseline: 3.7664x; 3.7664x over previous
//
#include <hip/hip_runtime.h>

#define BB 16
#define SS 1024
#define NPAD 1024      // padded matrix dim: real 1023 + identity pad row/col
#define NBLK 128
#define NSTEP 8        // NPAD / NBLK

// ---------- helpers ----------
__device__ __forceinline__ unsigned int enc_f32(float f) {
  unsigned int u = __float_as_uint(f);
  return (u & 0x80000000u) ? ~u : (u | 0x80000000u);
}
__device__ __forceinline__ float dec_key(unsigned int k) {
  unsigned int u = (k & 0x80000000u) ? (k & 0x7fffffffu) : ~k;
  return __uint_as_float(u);
}

// ---------- K0: init max key ----------
__global__ void __launch_bounds__(64) kinit(unsigned long long* mk) { *mk = 0ull; }

// ---------- K1: global max + argmax of scores ----------
__global__ void __launch_bounds__(256) kmax(const float* __restrict__ sc,
                                            unsigned long long* __restrict__ mk) {
  __shared__ unsigned long long red[256];
  const long long n = (long long)BB * SS * SS;
  unsigned long long best = 0ull;
  for (long long i = (long long)blockIdx.x * 256 + threadIdx.x; i < n;
       i += (long long)gridDim.x * 256) {
    unsigned long long k = ((unsigned long long)enc_f32(sc[i]) << 32) | (unsigned int)i;
    if (k > best) best = k;
  }
  red[threadIdx.x] = best;
  __syncthreads();
  for (int s = 128; s > 0; s >>= 1) {
    if ((int)threadIdx.x < s) {
      unsigned long long o = red[threadIdx.x + s];
      if (o > red[threadIdx.x]) red[threadIdx.x] = o;
    }
    __syncthreads();
  }
  if (threadIdx.x == 0) atomicMax(mk, red[0]);
}

// ---------- K2: build padded Laplacian minor M (row-dd M-matrix) ----------
__global__ void __launch_bounds__(256) kbuild(const float* __restrict__ sc,
                                              float* __restrict__ M,
                                              const unsigned long long* __restrict__ mk) {
  __shared__ float red[256];
  const int r = blockIdx.x;
  const int b = blockIdx.y;
  const int t = threadIdx.x;
  float* Mrow = M + ((size_t)b * NPAD + r) * NPAD;
  if (r == NPAD - 1) {
    for (int c = t; c < NPAD; c += 256) Mrow[c] = (c == NPAD - 1) ? 1.0f : 0.0f;
    return;
  }
  const float m = dec_key((unsigned int)(*mk >> 32));
  const int i = r + 1;
  const float* srow = sc + ((size_t)b * SS + i) * SS;
  float part = 0.f;
  for (int j = t; j < SS; j += 256) part += expf(srow[j] - m);
  red[t] = part;
  __syncthreads();
  for (int s = 128; s > 0; s >>= 1) {
    if (t < s) red[t] += red[t + s];
    __syncthreads();
  }
  const float rs = red[0];
  for (int c = t; c < NPAD; c += 256) {
    float v;
    if (c == NPAD - 1) v = 0.0f;
    else {
      v = -expf(srow[c + 1] - m);
      if (c == r) v += rs;
    }
    Mrow[c] = v;
  }
}

// ---------- K3a: copy block column kb of M into T ----------
__global__ void __launch_bounds__(256) kcopy(const float* __restrict__ M,
                                             float* __restrict__ T, int kb) {
  const int rt = blockIdx.x, b = blockIdx.y, t = threadIdx.x;
  const float* src = M + ((size_t)b * NPAD + rt * NBLK) * NPAD + kb * NBLK;
  float* dst = T + ((size_t)b * NPAD + rt * NBLK) * NBLK;
  const int c = (t & 31) * 4, r0 = t >> 5;
  for (int r = r0; r < NBLK; r += 8) {
    float4 v = *(const float4*)(src + (size_t)r * NPAD + c);
    *(float4*)(dst + r * NBLK + c) = v;
  }
}

// ---------- K3b: invert 128x128 diag block (register-resident Gauss-Jordan) ----------
// Static register indexing: kk = kd*16 + km, kd statically unrolled so r[kd][*] and
// r[*][kd] are true register accesses (previous version spilled to scratch: VGPR=32,
// 645 us/dispatch). 2 barriers/iter: publish UNNORMALIZED pivot row/col, every thread
// computes pinv locally from the broadcast rowbuf[kk].
__global__ void __launch_bounds__(256) kdiaginv(const float* __restrict__ T,
                                                float* __restrict__ D, int kb) {
  __shared__ float rowbuf[NBLK];
  __shared__ float colbuf[NBLK];
  const int b = blockIdx.x;
  const int t = threadIdx.x, tx = t & 15, ty = t >> 4;
  const float* src = T + ((size_t)b * NPAD + kb * NBLK) * NBLK;
  float r[8][8];
#pragma unroll
  for (int ii = 0; ii < 8; ii++)
#pragma unroll
    for (int jj = 0; jj < 8; jj++)
      r[ii][jj] = src[(ty + 16 * ii) * NBLK + tx + 16 * jj];

#pragma unroll
  for (int kd = 0; kd < 8; ++kd) {
    for (int km = 0; km < 16; ++km) {
      const int kk = kd * 16 + km;
      if (ty == km) {
#pragma unroll
        for (int jj = 0; jj < 8; jj++) rowbuf[tx + 16 * jj] = r[kd][jj];
      }
      if (tx == km) {
#pragma unroll
        for (int ii = 0; ii < 8; ii++) colbuf[ty + 16 * ii] = r[ii][kd];
      }
      __syncthreads();
      const float pinv = 1.0f / rowbuf[kk];
      // per-jj selects are ii-invariant: precompute
      float rb[8];
      bool zer[8];
#pragma unroll
      for (int jj = 0; jj < 8; jj++) {
        const int j = tx + 16 * jj;
        zer[jj] = (j == kk);
        rb[jj] = zer[jj] ? 1.0f : rowbuf[j];  // so old - cp*rb gives -cp at j==kk
      }
#pragma unroll
      for (int ii = 0; ii < 8; ii++) {
        const int i = ty + 16 * ii;
        if (i == kk) {
          // pivot row: normalize (only threads with ty==km, ii==kd hit this)
#pragma unroll
          for (int jj = 0; jj < 8; jj++)
            r[ii][jj] = zer[jj] ? pinv : r[ii][jj] * pinv;
        } else {
          const float cp = colbuf[i] * pinv;
#pragma unroll
          for (int jj = 0; jj < 8; jj++) {
            const float old = zer[jj] ? 0.0f : r[ii][jj];
            r[ii][jj] = old - cp * rb[jj];
          }
        }
      }
      __syncthreads();
    }
  }
  float* dst = D + (size_t)b * NBLK * NBLK;
#pragma unroll
  for (int ii = 0; ii < 8; ii++)
#pragma unroll
    for (int jj = 0; jj < 8; jj++)
      dst[(ty + 16 * ii) * NBLK + tx + 16 * jj] = r[ii][jj];
}

// ---------- shared 128x128x128 fp32 GEMM core: C = beta*C + alpha*A*B ----------
__device__ __forceinline__ void gemm128(const float* __restrict__ A, int lda,
                                        const float* __restrict__ B, int ldb,
                                        float* __restrict__ C, int ldc,
                                        float alpha, float beta) {
  __shared__ float As[16][132];  // As[k][i] = A[i][k0+k] (transposed; +4 pad)
  __shared__ float Bs[16][128];  // Bs[k][j] = B[k0+k][j]
  const int t = threadIdx.x, tx = t & 15, ty = t >> 4;
  float acc[8][8];
#pragma unroll
  for (int ii = 0; ii < 8; ii++)
#pragma unroll
    for (int jj = 0; jj < 8; jj++) acc[ii][jj] = 0.f;

  for (int k0 = 0; k0 < NBLK; k0 += 16) {
    {
      const int k = t & 15, i0 = t >> 4;
#pragma unroll
      for (int rr = 0; rr < 8; ++rr) {
        const int i = i0 + 16 * rr;
        As[k][i] = A[(size_t)i * lda + k0 + k];
      }
      const int j = t & 127, kb0 = t >> 7;
#pragma unroll
      for (int rr = 0; rr < 8; ++rr) {
        const int k2 = kb0 + 2 * rr;
        Bs[k2][j] = B[(size_t)(k0 + k2) * ldb + j];
      }
    }
    __syncthreads();
#pragma unroll
    for (int k = 0; k < 16; ++k) {
      float a[8], bv[8];
#pragma unroll
      for (int ii = 0; ii < 8; ii++) a[ii] = As[k][ty + 16 * ii];
#pragma unroll
      for (int jj = 0; jj < 8; jj++) bv[jj] = Bs[k][tx + 16 * jj];
#pragma unroll
      for (int ii = 0; ii < 8; ii++)
#pragma unroll
        for (int jj = 0; jj < 8; jj++) acc[ii][jj] += a[ii] * bv[jj];
    }
    __syncthreads();
  }
#pragma unroll
  for (int ii = 0; ii < 8; ii++)
#pragma unroll
    for (int jj = 0; jj < 8; jj++) {
      const int i = ty + 16 * ii, j = tx + 16 * jj;
      float* cp = C + (size_t)i * ldc + j;
      *cp = beta * (*cp) + alpha * acc[ii][jj];
    }
}

// ---------- K3c: pivot block-row scale ----------
__global__ void __launch_bounds__(256) kscale(float* __restrict__ M,
                                              const float* __restrict__ D, int kb) {
  const int jt = blockIdx.x, b = blockIdx.y;
  const float* Dinv = D + (size_t)b * NBLK * NBLK;
  float* Mb = M + (size_t)b * NPAD * NPAD;
  if (jt == kb) {
    const int t = threadIdx.x;
    const int c = (t & 31) * 4, r0 = t >> 5;
    float* dst = Mb + (size_t)(kb * NBLK) * NPAD + kb * NBLK;
    for (int r = r0; r < NBLK; r += 8)
      *(float4*)(dst + (size_t)r * NPAD + c) = *(const float4*)(Dinv + r * NBLK + c);
    return;
  }
  float* Btile = Mb + (size_t)(kb * NBLK) * NPAD + jt * NBLK;
  gemm128(Dinv, NBLK, Btile, NPAD, Btile, NPAD, 1.0f, 0.0f);
}

// ---------- K3d: trailing update (and pivot-column): rows it != kb ----------
__global__ void __launch_bounds__(256) kupdate(float* __restrict__ M,
                                               const float* __restrict__ T,
                                               const float* __restrict__ D, int kb) {
  const int jt = blockIdx.x;
  int it = blockIdx.y; it = (it >= kb) ? it + 1 : it;
  const int b = blockIdx.z;
  float* Mb = M + (size_t)b * NPAD * NPAD;
  const float* Atile = T + ((size_t)b * NPAD + it * NBLK) * NBLK;
  float* Ctile = Mb + (size_t)(it * NBLK) * NPAD + jt * NBLK;
  if (jt == kb) {
    gemm128(Atile, NBLK, D + (size_t)b * NBLK * NBLK, NBLK, Ctile, NPAD, -1.0f, 0.0f);
  } else {
    const float* Btile = Mb + (size_t)(kb * NBLK) * NPAD + jt * NBLK;
    gemm128(Atile, NBLK, Btile, NPAD, Ctile, NPAD, -1.0f, 1.0f);
  }
}

// ---------- K4: epilogue: probs = A .* (Binv[p,p] - Binv[q,p]) + spike ----------
__global__ void __launch_bounds__(256) kfinal(const float* __restrict__ sc,
                                              const float* __restrict__ Minv,
                                              float* __restrict__ out,
                                              const unsigned long long* __restrict__ mk) {
  __shared__ float Ls[64][65];
  __shared__ float Ds[64];
  const int qt = blockIdx.x, pt = blockIdx.y, b = blockIdx.z;
  const int t = threadIdx.x;
  const unsigned long long key = *mk;
  const float m = dec_key((unsigned int)(key >> 32));
  const unsigned int amax = (unsigned int)key;
  const float* Mb = Minv + (size_t)b * NPAD * NPAD;
  const int q0 = qt * 64, p0 = pt * 64;
  {
    const int pp = t & 63, qq0 = t >> 6;
#pragma unroll
    for (int rp = 0; rp < 16; ++rp) {
      const int qq = qq0 + 4 * rp;
      int rrow = q0 + qq - 1; if (rrow < 0) rrow = 0;
      int ccol = p0 + pp - 1; if (ccol < 0) ccol = 0;
      Ls[qq][pp] = Mb[(size_t)rrow * NPAD + ccol];
    }
    if (t < 64) {
      int cc = p0 + t - 1; if (cc < 0) cc = 0;
      Ds[t] = Mb[(size_t)cc * NPAD + cc];
    }
  }
  __syncthreads();
  const int qq = t & 63, pp0 = t >> 6;
#pragma unroll
  for (int rp = 0; rp < 16; ++rp) {
    const int pp = pp0 + 4 * rp;
    const int p = p0 + pp, q = q0 + qq;
    const size_t off = ((size_t)b * SS + p) * SS + q;
    float val = 0.f;
    if (p >= 1) {
      const float a = expf(sc[off] - m);
      const float g = Ds[pp] - ((q >= 1) ? Ls[qq][pp] : 0.f);
      val = a * g;
    }
    if ((unsigned int)off == amax) val += 16.0f;  // d logZ / d m
    out[off] = val;
  }
}

extern "C" void kernel_launch(void* const* d_in, const int* in_sizes, int n_in,
                              void* d_out, int out_size, void* d_ws, size_t ws_size,
                              hipStream_t stream) {
  const float* sc = (const float*)d_in[0];
  float* out = (float*)d_out;
  char* ws = (char*)d_ws;
  unsigned long long* mk = (unsigned long long*)ws;
  float* M = (float*)(ws + 256);
  float* T = M + (size_t)BB * NPAD * NPAD;
  float* D = T + (size_t)BB * NPAD * NBLK;

  hipLaunchKernelGGL(kinit, dim3(1), dim3(64), 0, stream, mk);
  hipLaunchKernelGGL(kmax, dim3(1024), dim3(256), 0, stream, sc, mk);
  hipLaunchKernelGGL(kbuild, dim3(NPAD, BB), dim3(256), 0, stream, sc, M, mk);
  for (int kb = 0; kb < NSTEP; ++kb) {
    hipLaunchKernelGGL(kcopy, dim3(NSTEP, BB), dim3(256), 0, stream, M, T, kb);
    hipLaunchKernelGGL(kdiaginv, dim3(BB), dim3(256), 0, stream, T, D, kb);
    hipLaunchKernelGGL(kscale, dim3(NSTEP, BB), dim3(256), 0, stream, M, D, kb);
    hipLaunchKernelGGL(kupdate, dim3(NSTEP, NSTEP - 1, BB), dim3(256), 0, stream, M, T, D, kb);
  }
  hipLaunchKernelGGL(kfinal, dim3(16, 16, BB), dim3(256), 0, stream, sc, M, out, mk);
}

// Round 3
// 1310.138 us; speedup vs baseline: 4.7290x; 1.2556x over previous
//
#include <hip/hip_runtime.h>

#define BB 16
#define SS 1024
#define NPAD 1024      // padded matrix dim: real 1023 + identity pad row/col
#define NBLK 128
#define NSTEP 8        // NPAD / NBLK

typedef __attribute__((ext_vector_type(8))) __bf16 bf16x8;
typedef __attribute__((ext_vector_type(4))) float f32x4;

// ---------- helpers ----------
__device__ __forceinline__ unsigned int enc_f32(float f) {
  unsigned int u = __float_as_uint(f);
  return (u & 0x80000000u) ? ~u : (u | 0x80000000u);
}
__device__ __forceinline__ float dec_key(unsigned int k) {
  unsigned int u = (k & 0x80000000u) ? (k & 0x7fffffffu) : ~k;
  return __uint_as_float(u);
}

// ---------- K0: init max key ----------
__global__ void __launch_bounds__(64) kinit(unsigned long long* mk) { *mk = 0ull; }

// ---------- K1: global max + argmax of scores ----------
__global__ void __launch_bounds__(256) kmax(const float* __restrict__ sc,
                                            unsigned long long* __restrict__ mk) {
  __shared__ unsigned long long red[256];
  const long long n = (long long)BB * SS * SS;
  unsigned long long best = 0ull;
  for (long long i = (long long)blockIdx.x * 256 + threadIdx.x; i < n;
       i += (long long)gridDim.x * 256) {
    unsigned long long k = ((unsigned long long)enc_f32(sc[i]) << 32) | (unsigned int)i;
    if (k > best) best = k;
  }
  red[threadIdx.x] = best;
  __syncthreads();
  for (int s = 128; s > 0; s >>= 1) {
    if ((int)threadIdx.x < s) {
      unsigned long long o = red[threadIdx.x + s];
      if (o > red[threadIdx.x]) red[threadIdx.x] = o;
    }
    __syncthreads();
  }
  if (threadIdx.x == 0) atomicMax(mk, red[0]);
}

// ---------- K2: build padded Laplacian minor M ----------
__global__ void __launch_bounds__(256) kbuild(const float* __restrict__ sc,
                                              float* __restrict__ M,
                                              const unsigned long long* __restrict__ mk) {
  __shared__ float red[256];
  const int r = blockIdx.x;
  const int b = blockIdx.y;
  const int t = threadIdx.x;
  float* Mrow = M + ((size_t)b * NPAD + r) * NPAD;
  if (r == NPAD - 1) {
    for (int c = t; c < NPAD; c += 256) Mrow[c] = (c == NPAD - 1) ? 1.0f : 0.0f;
    return;
  }
  const float m = dec_key((unsigned int)(*mk >> 32));
  const int i = r + 1;
  const float* srow = sc + ((size_t)b * SS + i) * SS;
  float part = 0.f;
  for (int j = t; j < SS; j += 256) part += expf(srow[j] - m);
  red[t] = part;
  __syncthreads();
  for (int s = 128; s > 0; s >>= 1) {
    if (t < s) red[t] += red[t + s];
    __syncthreads();
  }
  const float rs = red[0];
  for (int c = t; c < NPAD; c += 256) {
    float v;
    if (c == NPAD - 1) v = 0.0f;
    else {
      v = -expf(srow[c + 1] - m);
      if (c == r) v += rs;
    }
    Mrow[c] = v;
  }
}

// ---------- fused K3a+K3b: copy column panel to T (128 blocks) + GJ diag inverse (16 blocks) ----------
__global__ void __launch_bounds__(256) kcopydiag(const float* __restrict__ M,
                                                 float* __restrict__ T,
                                                 float* __restrict__ D, int kb) {
  const int x = blockIdx.x;
  const int t = threadIdx.x;
  if (x < NSTEP * BB) {
    // copy tile (rt, kb) of batch b into T
    const int rt = x >> 4, b = x & 15;
    const float* src = M + ((size_t)b * NPAD + rt * NBLK) * NPAD + kb * NBLK;
    float* dst = T + ((size_t)b * NPAD + rt * NBLK) * NBLK;
    const int c = (t & 31) * 4, r0 = t >> 5;
    for (int r = r0; r < NBLK; r += 8) {
      float4 v = *(const float4*)(src + (size_t)r * NPAD + c);
      *(float4*)(dst + r * NBLK + c) = v;
    }
    return;
  }
  // register-resident Gauss-Jordan inverse of tile (kb,kb), read directly from M
  __shared__ float rowbuf[NBLK];
  __shared__ float colbuf[NBLK];
  const int b = x - NSTEP * BB;
  const int tx = t & 15, ty = t >> 4;
  const float* src = M + ((size_t)b * NPAD + kb * NBLK) * NPAD + kb * NBLK;
  float r[8][8];
#pragma unroll
  for (int ii = 0; ii < 8; ii++)
#pragma unroll
    for (int jj = 0; jj < 8; jj++)
      r[ii][jj] = src[(size_t)(ty + 16 * ii) * NPAD + tx + 16 * jj];

#pragma unroll
  for (int kd = 0; kd < 8; ++kd) {
    for (int km = 0; km < 16; ++km) {
      const int kk = kd * 16 + km;
      if (ty == km) {
#pragma unroll
        for (int jj = 0; jj < 8; jj++) rowbuf[tx + 16 * jj] = r[kd][jj];
      }
      if (tx == km) {
#pragma unroll
        for (int ii = 0; ii < 8; ii++) colbuf[ty + 16 * ii] = r[ii][kd];
      }
      __syncthreads();
      const float pinv = 1.0f / rowbuf[kk];
      float rb[8];
      bool zer[8];
#pragma unroll
      for (int jj = 0; jj < 8; jj++) {
        const int j = tx + 16 * jj;
        zer[jj] = (j == kk);
        rb[jj] = zer[jj] ? 1.0f : rowbuf[j];
      }
#pragma unroll
      for (int ii = 0; ii < 8; ii++) {
        const int i = ty + 16 * ii;
        if (i == kk) {
#pragma unroll
          for (int jj = 0; jj < 8; jj++)
            r[ii][jj] = zer[jj] ? pinv : r[ii][jj] * pinv;
        } else {
          const float cp = colbuf[i] * pinv;
#pragma unroll
          for (int jj = 0; jj < 8; jj++) {
            const float old = zer[jj] ? 0.0f : r[ii][jj];
            r[ii][jj] = old - cp * rb[jj];
          }
        }
      }
      __syncthreads();
    }
  }
  float* dst = D + (size_t)b * NBLK * NBLK;
#pragma unroll
  for (int ii = 0; ii < 8; ii++)
#pragma unroll
    for (int jj = 0; jj < 8; jj++)
      dst[(ty + 16 * ii) * NBLK + tx + 16 * jj] = r[ii][jj];
}

// ---------- 128x128x128 GEMM core via split-bf16 MFMA: C = beta*C + alpha*A*B ----------
// a = ah + al (bf16 hi/lo), product = ah*bh + ah*bl + al*bh, fp32 accumulate in AGPRs.
// LDS fragment-packed layouts (verified m89/m91/m120):
//   A-frag: lane l holds A[m=l&15][k=(l>>4)*8+j]  -> pack idx ((R*4+q)*16+m)*8+j
//   B-frag: lane l holds B[k=(l>>4)*8+j][n=l&15]  -> pack idx ((CT*4+q)*16+n)*8+j
//   C/D:    col=l&15, row=(l>>4)*4+reg
__device__ __forceinline__ void gemm128(const float* __restrict__ A, int lda,
                                        const float* __restrict__ B, int ldb,
                                        float* __restrict__ C, int ldc,
                                        float alpha, float beta) {
  __shared__ __bf16 Ah[4096], Al[4096], Bh[4096], Bl[4096];
  const int t = threadIdx.x;
  const int l = t & 63, w = t >> 6;
  const int ic = t & 127, kh = t >> 7;  // staging row/col id, k-half (0/1)
  const int rbase = (w & 1) * 4, cbase = (w >> 1) * 4;

  f32x4 acc[4][4];
#pragma unroll
  for (int i = 0; i < 4; i++)
#pragma unroll
    for (int j = 0; j < 4; j++) acc[i][j] = (f32x4){0.f, 0.f, 0.f, 0.f};

  for (int k0 = 0; k0 < NBLK; k0 += 32) {
    // stage A: thread owns row ic, 16 consecutive k (vectorized global read)
    {
      const float* ap = A + (size_t)ic * lda + k0 + kh * 16;
      float f[16];
      *(float4*)(f + 0)  = *(const float4*)(ap + 0);
      *(float4*)(f + 4)  = *(const float4*)(ap + 4);
      *(float4*)(f + 8)  = *(const float4*)(ap + 8);
      *(float4*)(f + 12) = *(const float4*)(ap + 12);
      const int base = ((ic >> 4) * 4 + kh * 2) * 16 + (ic & 15);
#pragma unroll
      for (int g = 0; g < 2; ++g) {
        bf16x8 hv, lv;
#pragma unroll
        for (int j = 0; j < 8; ++j) {
          float x = f[g * 8 + j];
          __bf16 h = (__bf16)x;
          hv[j] = h;
          lv[j] = (__bf16)(x - (float)h);
        }
        *(bf16x8*)&Ah[(size_t)(base + g * 16) * 8] = hv;
        *(bf16x8*)&Al[(size_t)(base + g * 16) * 8] = lv;
      }
    }
    // stage B: thread owns col ic, 16 strided k (coalesced across lanes)
    {
      const float* bp = B + (size_t)(k0 + kh * 16) * ldb + ic;
      float f[16];
#pragma unroll
      for (int kk = 0; kk < 16; ++kk) f[kk] = bp[(size_t)kk * ldb];
      const int base = ((ic >> 4) * 4 + kh * 2) * 16 + (ic & 15);
#pragma unroll
      for (int g = 0; g < 2; ++g) {
        bf16x8 hv, lv;
#pragma unroll
        for (int j = 0; j < 8; ++j) {
          float x = f[g * 8 + j];
          __bf16 h = (__bf16)x;
          hv[j] = h;
          lv[j] = (__bf16)(x - (float)h);
        }
        *(bf16x8*)&Bh[(size_t)(base + g * 16) * 8] = hv;
        *(bf16x8*)&Bl[(size_t)(base + g * 16) * 8] = lv;
      }
    }
    __syncthreads();
    bf16x8 a_h[4], a_l[4];
#pragma unroll
    for (int rt = 0; rt < 4; ++rt) {
      a_h[rt] = *(const bf16x8*)&Ah[(size_t)((rbase + rt) * 64 + l) * 8];
      a_l[rt] = *(const bf16x8*)&Al[(size_t)((rbase + rt) * 64 + l) * 8];
    }
#pragma unroll
    for (int ct = 0; ct < 4; ++ct) {
      bf16x8 b_h = *(const bf16x8*)&Bh[(size_t)((cbase + ct) * 64 + l) * 8];
      bf16x8 b_l = *(const bf16x8*)&Bl[(size_t)((cbase + ct) * 64 + l) * 8];
#pragma unroll
      for (int rt = 0; rt < 4; ++rt) {
        acc[rt][ct] = __builtin_amdgcn_mfma_f32_16x16x32_bf16(a_h[rt], b_h, acc[rt][ct], 0, 0, 0);
        acc[rt][ct] = __builtin_amdgcn_mfma_f32_16x16x32_bf16(a_h[rt], b_l, acc[rt][ct], 0, 0, 0);
        acc[rt][ct] = __builtin_amdgcn_mfma_f32_16x16x32_bf16(a_l[rt], b_h, acc[rt][ct], 0, 0, 0);
      }
    }
    __syncthreads();
  }
  // epilogue: C/D layout col=l&15, row=(l>>4)*4+reg
  const int row0 = (w & 1) * 64 + ((l >> 4) << 2);
  const int col0 = (w >> 1) * 64 + (l & 15);
  if (beta == 0.0f) {
#pragma unroll
    for (int rt = 0; rt < 4; ++rt)
#pragma unroll
      for (int ct = 0; ct < 4; ++ct)
#pragma unroll
        for (int r = 0; r < 4; ++r)
          C[(size_t)(row0 + rt * 16 + r) * ldc + col0 + ct * 16] = alpha * acc[rt][ct][r];
  } else {
#pragma unroll
    for (int rt = 0; rt < 4; ++rt)
#pragma unroll
      for (int ct = 0; ct < 4; ++ct)
#pragma unroll
        for (int r = 0; r < 4; ++r) {
          float* cp = C + (size_t)(row0 + rt * 16 + r) * ldc + col0 + ct * 16;
          *cp = beta * (*cp) + alpha * acc[rt][ct][r];
        }
  }
}

// ---------- K3c: pivot block-row scale ----------
__global__ void __launch_bounds__(256) kscale(float* __restrict__ M,
                                              const float* __restrict__ D, int kb) {
  const int jt = blockIdx.x, b = blockIdx.y;
  const float* Dinv = D + (size_t)b * NBLK * NBLK;
  float* Mb = M + (size_t)b * NPAD * NPAD;
  if (jt == kb) {
    const int t = threadIdx.x;
    const int c = (t & 31) * 4, r0 = t >> 5;
    float* dst = Mb + (size_t)(kb * NBLK) * NPAD + kb * NBLK;
    for (int r = r0; r < NBLK; r += 8)
      *(float4*)(dst + (size_t)r * NPAD + c) = *(const float4*)(Dinv + r * NBLK + c);
    return;
  }
  float* Btile = Mb + (size_t)(kb * NBLK) * NPAD + jt * NBLK;
  gemm128(Dinv, NBLK, Btile, NPAD, Btile, NPAD, 1.0f, 0.0f);
}

// ---------- K3d: trailing update (and pivot-column): rows it != kb ----------
__global__ void __launch_bounds__(256) kupdate(float* __restrict__ M,
                                               const float* __restrict__ T,
                                               const float* __restrict__ D, int kb) {
  const int jt = blockIdx.x;
  int it = blockIdx.y; it = (it >= kb) ? it + 1 : it;
  const int b = blockIdx.z;
  float* Mb = M + (size_t)b * NPAD * NPAD;
  const float* Atile = T + ((size_t)b * NPAD + it * NBLK) * NBLK;
  float* Ctile = Mb + (size_t)(it * NBLK) * NPAD + jt * NBLK;
  if (jt == kb) {
    gemm128(Atile, NBLK, D + (size_t)b * NBLK * NBLK, NBLK, Ctile, NPAD, -1.0f, 0.0f);
  } else {
    const float* Btile = Mb + (size_t)(kb * NBLK) * NPAD + jt * NBLK;
    gemm128(Atile, NBLK, Btile, NPAD, Ctile, NPAD, -1.0f, 1.0f);
  }
}

// ---------- K4: epilogue: probs = A .* (Binv[p,p] - Binv[q,p]) + spike ----------
__global__ void __launch_bounds__(256) kfinal(const float* __restrict__ sc,
                                              const float* __restrict__ Minv,
                                              float* __restrict__ out,
                                              const unsigned long long* __restrict__ mk) {
  __shared__ float Ls[64][65];
  __shared__ float Ds[64];
  const int qt = blockIdx.x, pt = blockIdx.y, b = blockIdx.z;
  const int t = threadIdx.x;
  const unsigned long long key = *mk;
  const float m = dec_key((unsigned int)(key >> 32));
  const unsigned int amax = (unsigned int)key;
  const float* Mb = Minv + (size_t)b * NPAD * NPAD;
  const int q0 = qt * 64, p0 = pt * 64;
  {
    const int pp = t & 63, qq0 = t >> 6;
#pragma unroll
    for (int rp = 0; rp < 16; ++rp) {
      const int qq = qq0 + 4 * rp;
      int rrow = q0 + qq - 1; if (rrow < 0) rrow = 0;
      int ccol = p0 + pp - 1; if (ccol < 0) ccol = 0;
      Ls[qq][pp] = Mb[(size_t)rrow * NPAD + ccol];
    }
    if (t < 64) {
      int cc = p0 + t - 1; if (cc < 0) cc = 0;
      Ds[t] = Mb[(size_t)cc * NPAD + cc];
    }
  }
  __syncthreads();
  const int qq = t & 63, pp0 = t >> 6;
#pragma unroll
  for (int rp = 0; rp < 16; ++rp) {
    const int pp = pp0 + 4 * rp;
    const int p = p0 + pp, q = q0 + qq;
    const size_t off = ((size_t)b * SS + p) * SS + q;
    float val = 0.f;
    if (p >= 1) {
      const float a = expf(sc[off] - m);
      const float g = Ds[pp] - ((q >= 1) ? Ls[qq][pp] : 0.f);
      val = a * g;
    }
    if ((unsigned int)off == amax) val += 16.0f;  // d logZ / d m
    out[off] = val;
  }
}

extern "C" void kernel_launch(void* const* d_in, const int* in_sizes, int n_in,
                              void* d_out, int out_size, void* d_ws, size_t ws_size,
                              hipStream_t stream) {
  const float* sc = (const float*)d_in[0];
  float* out = (float*)d_out;
  char* ws = (char*)d_ws;
  unsigned long long* mk = (unsigned long long*)ws;
  float* M = (float*)(ws + 256);
  float* T = M + (size_t)BB * NPAD * NPAD;
  float* D = T + (size_t)BB * NPAD * NBLK;

  hipLaunchKernelGGL(kinit, dim3(1), dim3(64), 0, stream, mk);
  hipLaunchKernelGGL(kmax, dim3(1024), dim3(256), 0, stream, sc, mk);
  hipLaunchKernelGGL(kbuild, dim3(NPAD, BB), dim3(256), 0, stream, sc, M, mk);
  for (int kb = 0; kb < NSTEP; ++kb) {
    hipLaunchKernelGGL(kcopydiag, dim3(NSTEP * BB + BB), dim3(256), 0, stream, M, T, D, kb);
    hipLaunchKernelGGL(kscale, dim3(NSTEP, BB), dim3(256), 0, stream, M, D, kb);
    hipLaunchKernelGGL(kupdate, dim3(NSTEP, NSTEP - 1, BB), dim3(256), 0, stream, M, T, D, kb);
  }
  hipLaunchKernelGGL(kfinal, dim3(16, 16, BB), dim3(256), 0, stream, sc, M, out, mk);
}